// Round 9
// baseline (374.449 us; speedup 1.0000x reference)
//
#include <hip/hip_runtime.h>
#include <hip/hip_bf16.h>
#include <math.h>
#include <type_traits>

#define FDIM 128     // in/hid feature dim
#define ODIM 40      // output classes

typedef __attribute__((ext_vector_type(8))) short bf16x8;
typedef __attribute__((ext_vector_type(4))) float f32x4;

// ---- bf16 pack/unpack helpers (manual, RNE) --------------------------------
__device__ __forceinline__ float bf_lo(unsigned v) { return __uint_as_float(v << 16); }
__device__ __forceinline__ float bf_hi(unsigned v) { return __uint_as_float(v & 0xFFFF0000u); }
__device__ __forceinline__ unsigned f2bf(float f) {   // round-to-nearest-even
    unsigned u = __float_as_uint(f);
    return (u + 0x7FFFu + ((u >> 16) & 1u)) >> 16;
}

// ---------------------------------------------------------------------------
// 1) count in-degrees (dst atomics) + convert W1/W2 -> Wt bf16 (fused)
// ---------------------------------------------------------------------------
__global__ void count_conv_k(const int* __restrict__ dst, int* __restrict__ count, int E,
                             const float* __restrict__ W1, const float* __restrict__ W2,
                             unsigned short* __restrict__ Wt1, unsigned short* __restrict__ Wt2) {
    int e = blockIdx.x * 256 + threadIdx.x;
    if (e < E) atomicAdd(&count[dst[e]], 1);
    if (e < 2 * 16384) {                       // first 128 blocks also transpose weights
        const float* W = (e < 16384) ? W1 : W2;
        unsigned short* Wt = (e < 16384) ? Wt1 : Wt2;
        int j = e & 16383;
        int k = j >> 7, n = j & 127;
        Wt[n * 128 + k] = (unsigned short)f2bf(W[k * 128 + n]);
    }
}

// ---------------------------------------------------------------------------
// 2) single-pass decoupled-lookback exclusive scan over count[N] (1024/block)
// ---------------------------------------------------------------------------
#define FLG_AGG (1ull << 62)
#define FLG_INC (2ull << 62)
__global__ __launch_bounds__(256) void scan_lookback_k(
        const int* __restrict__ count, unsigned long long* __restrict__ states,
        int* __restrict__ rowptr, int* __restrict__ cursor,
        float* __restrict__ dinv, int n, int nblocks) {
    __shared__ int ts[256];
    __shared__ int s_prefix;
    const int b = blockIdx.x, tid = threadIdx.x;
    const int base = b * 1024 + tid * 4;
    int c[4];
    int s = 0;
#pragma unroll
    for (int j = 0; j < 4; ++j) {
        int i = base + j;
        c[j] = (i < n) ? count[i] : 0;
        s += c[j];
    }
    ts[tid] = s;
    __syncthreads();
    for (int off = 1; off < 256; off <<= 1) {   // Hillis-Steele inclusive
        int v = (tid >= off) ? ts[tid - off] : 0;
        __syncthreads();
        ts[tid] += v;
        __syncthreads();
    }
    const int total = ts[255];
    if (tid == 0) {
        if (b == 0) {
            __hip_atomic_store(&states[0], FLG_INC | (unsigned long long)total,
                               __ATOMIC_RELAXED, __HIP_MEMORY_SCOPE_AGENT);
            s_prefix = 0;
        } else {
            __hip_atomic_store(&states[b], FLG_AGG | (unsigned long long)total,
                               __ATOMIC_RELAXED, __HIP_MEMORY_SCOPE_AGENT);
            int prefix = 0;
            int j = b - 1;
            while (true) {
                unsigned long long v = __hip_atomic_load(&states[j], __ATOMIC_RELAXED,
                                                         __HIP_MEMORY_SCOPE_AGENT);
                unsigned long long f = v >> 62;
                if (f == 2ull) { prefix += (int)(v & 0xFFFFFFFFull); break; }
                if (f == 1ull) { prefix += (int)(v & 0xFFFFFFFFull); --j; }
                else __builtin_amdgcn_s_sleep(1);
            }
            __hip_atomic_store(&states[b], FLG_INC | (unsigned long long)(prefix + total),
                               __ATOMIC_RELAXED, __HIP_MEMORY_SCOPE_AGENT);
            s_prefix = prefix;
        }
    }
    __syncthreads();
    int excl = s_prefix + ts[tid] - s;
#pragma unroll
    for (int j = 0; j < 4; ++j) {
        int i = base + j;
        if (i < n) {
            rowptr[i] = excl;
            cursor[i] = excl;
            dinv[i] = rsqrtf((float)(c[j] + 1));
        }
        excl += c[j];
    }
    if (b == nblocks - 1 && tid == 255) rowptr[n] = s_prefix + total;
}

// ---------------------------------------------------------------------------
// 3) fill CSR: src ids grouped by dst
// ---------------------------------------------------------------------------
__global__ void fill_csr_k(const int* __restrict__ src, const int* __restrict__ dst,
                           int* __restrict__ cursor, int* __restrict__ csr_src, int E) {
    int e = blockIdx.x * blockDim.x + threadIdx.x;
    if (e < E) {
        int d = dst[e];
        int p = atomicAdd(&cursor[d], 1);
        csr_src[p] = src[e];
    }
}

// ---------------------------------------------------------------------------
// 4) MFMA GEMM: Cb[M,128](bf16) = (A[M,128] @ W) * dinv[row]
// ---------------------------------------------------------------------------
template <typename AT>
__global__ __launch_bounds__(256) void mfma_gemm_k(const AT* __restrict__ A,
                                                   const unsigned short* __restrict__ Wt,
                                                   const float* __restrict__ dinv,
                                                   unsigned short* __restrict__ Cb, int M) {
    __shared__ unsigned short As[64][136];   // row stride 272 B = 4 banks mod 32
    __shared__ unsigned short Bs[128][136];

    const int tid = threadIdx.x;
    const int row0 = blockIdx.x * 64;

    // ---- stage A (64 x 128) ----
    if constexpr (std::is_same_v<AT, float>) {
#pragma unroll
        for (int i = 0; i < 8; ++i) {        // 64 rows * 32 float4 = 2048
            int fidx = i * 256 + tid;
            int r = fidx >> 5, kq = fidx & 31;
            float4 v = make_float4(0.f, 0.f, 0.f, 0.f);
            int grow = row0 + r;
            if (grow < M) v = *(const float4*)&A[(size_t)grow * 128 + kq * 4];
            unsigned lo = f2bf(v.x) | (f2bf(v.y) << 16);
            unsigned hi = f2bf(v.z) | (f2bf(v.w) << 16);
            *(uint2*)&As[r][kq * 4] = make_uint2(lo, hi);
        }
    } else {
#pragma unroll
        for (int i = 0; i < 4; ++i) {        // 64 rows * 16 uint4 = 1024
            int fidx = i * 256 + tid;
            int r = fidx >> 4, kq = fidx & 15;
            uint4 v = make_uint4(0, 0, 0, 0);
            int grow = row0 + r;
            if (grow < M) v = *(const uint4*)&A[(size_t)grow * 128 + kq * 8];
            *(uint4*)&As[r][kq * 8] = v;
        }
    }
    // ---- stage B (128 x 128) ----
#pragma unroll
    for (int i = 0; i < 8; ++i) {            // 128 rows * 16 uint4 = 2048
        int fidx = i * 256 + tid;
        int r = fidx >> 4, kq = fidx & 15;
        *(uint4*)&Bs[r][kq * 8] = *(const uint4*)&Wt[(size_t)r * 128 + kq * 8];
    }
    __syncthreads();

    // ---- compute ----
    const int lane = tid & 63;
    const int wv = tid >> 6;       // wave 0..3 -> cols wv*32 .. +31
    const int n0 = wv * 32;
    const int mrow = lane & 15;
    const int quad = lane >> 4;

    f32x4 acc[4][2];
#pragma unroll
    for (int mt = 0; mt < 4; ++mt)
#pragma unroll
        for (int nt = 0; nt < 2; ++nt) acc[mt][nt] = (f32x4){0.f, 0.f, 0.f, 0.f};

#pragma unroll
    for (int kk = 0; kk < 128; kk += 32) {
        int ko = kk + quad * 8;
        bf16x8 af[4], bfr[2];
#pragma unroll
        for (int mt = 0; mt < 4; ++mt) af[mt] = *(const bf16x8*)&As[mt * 16 + mrow][ko];
#pragma unroll
        for (int nt = 0; nt < 2; ++nt) bfr[nt] = *(const bf16x8*)&Bs[n0 + nt * 16 + mrow][ko];
#pragma unroll
        for (int mt = 0; mt < 4; ++mt)
#pragma unroll
            for (int nt = 0; nt < 2; ++nt)
                acc[mt][nt] = __builtin_amdgcn_mfma_f32_16x16x32_bf16(af[mt], bfr[nt], acc[mt][nt], 0, 0, 0);
    }

    // ---- epilogue: C layout col=lane&15, row=quad*4+reg ----
#pragma unroll
    for (int mt = 0; mt < 4; ++mt) {
#pragma unroll
        for (int reg = 0; reg < 4; ++reg) {
            int grow = row0 + mt * 16 + quad * 4 + reg;
            if (grow < M) {
                float sc = dinv[grow];
#pragma unroll
                for (int nt = 0; nt < 2; ++nt) {
                    int col = n0 + nt * 16 + mrow;
                    Cb[(size_t)grow * 128 + col] = (unsigned short)f2bf(acc[mt][nt][reg] * sc);
                }
            }
        }
    }
}

// ---------------------------------------------------------------------------
// 5) channel-blocked aggregate: 4 passes of 32 channels.
//    Per pass the touched slice of g is N*64 B = 3.2 MB < 4 MB per-XCD L2, so
//    edge gathers hit L2 instead of L3/HBM. Pass = blockIdx.x / npb (dispatch
//    order gives temporal separation; correctness does not depend on it).
//    Wave layout: 1 wave per dst node; lanes = 4 edge-slots x 16 ch-lanes
//    (4 B = 2 bf16 channels each); cross-slot reduce via shfl_xor(16,32).
// ---------------------------------------------------------------------------
template <bool RELU, bool OUT_BF16>
__global__ __launch_bounds__(256) void agg_pass_k(const unsigned* __restrict__ g,
                                                  const float* __restrict__ dinv,
                                                  const int* __restrict__ rowptr,
                                                  const int* __restrict__ csr,
                                                  const float* __restrict__ bias,
                                                  void* __restrict__ outv, int n, int npb) {
    const int tid = threadIdx.x;
    const int wv = tid >> 6;             // wave in block: 0..3
    const int lane = tid & 63;
    const int esub = lane >> 4;          // edge slot 0..3
    const int ch = lane & 15;            // uint index within 64 B quarter-row
    const int pass = blockIdx.x / npb;   // channel quarter 0..3
    const int d = (blockIdx.x - pass * npb) * 4 + wv;
    if (d >= n) return;                  // wave-uniform exit (shuffles below safe)
    const unsigned* gq = g + pass * 16;  // quarter offset (16 uints = 32 ch)

    float ax = 0.f, ay = 0.f;
    if (esub == 0) {                     // self-loop term (one slot only)
        unsigned v = gq[(size_t)d * 64 + ch];
        ax = bf_lo(v); ay = bf_hi(v);
    }
    int e = rowptr[d];
    const int end = rowptr[d + 1];
    for (; e + 7 < end; e += 8) {        // 8 edges in flight (2 loads/lane)
        int s0 = csr[e + esub], s1 = csr[e + 4 + esub];
        unsigned v0 = gq[(size_t)s0 * 64 + ch];
        unsigned v1 = gq[(size_t)s1 * 64 + ch];
        ax += bf_lo(v0) + bf_lo(v1);
        ay += bf_hi(v0) + bf_hi(v1);
    }
    for (; e < end; e += 4) {
        int idx = e + esub;
        if (idx < end) {
            int s = csr[idx];
            unsigned v = gq[(size_t)s * 64 + ch];
            ax += bf_lo(v); ay += bf_hi(v);
        }
    }
    // reduce the 4 edge slots (lanes ch, ch+16, ch+32, ch+48)
    ax += __shfl_xor(ax, 16); ay += __shfl_xor(ay, 16);
    ax += __shfl_xor(ax, 32); ay += __shfl_xor(ay, 32);
    if (esub == 0) {
        float sc = dinv[d];
        int c0 = pass * 32 + ch * 2;
        float ox = fmaf(sc, ax, bias[c0]);
        float oy = fmaf(sc, ay, bias[c0 + 1]);
        if (RELU) { ox = fmaxf(ox, 0.f); oy = fmaxf(oy, 0.f); }
        if constexpr (OUT_BF16) {
            ((unsigned*)outv)[(size_t)d * 64 + pass * 16 + ch] = f2bf(ox) | (f2bf(oy) << 16);
        } else {
            ((float2*)outv)[(size_t)d * 64 + pass * 16 + ch] = make_float2(ox, oy);
        }
    }
}

// ---------------------------------------------------------------------------
// 6) logits = x_emb @ Wl + bl; log_softmax over 40 cols.
// ---------------------------------------------------------------------------
__global__ __launch_bounds__(256) void logits_lsm_k(const float* __restrict__ xe,
                                                    const float* __restrict__ Wl,
                                                    const float* __restrict__ bl,
                                                    float* __restrict__ out, int M) {
    __shared__ float sW[128 * 40];
    __shared__ float sX[32][132];
    __shared__ float sB[40];
    const int tid = threadIdx.x;
    const int row0 = blockIdx.x * 32;

    for (int i = tid; i < (128 * 40) / 4; i += 256)
        ((float4*)sW)[i] = ((const float4*)Wl)[i];
    if (tid < 40) sB[tid] = bl[tid];
    for (int i = tid; i < 32 * 32; i += 256) {
        int r = i >> 5, cq = i & 31;
        float4 v = make_float4(0.f, 0.f, 0.f, 0.f);
        if (row0 + r < M) v = *(const float4*)&xe[(size_t)(row0 + r) * 128 + cq * 4];
        *(float4*)&sX[r][cq * 4] = v;
    }
    __syncthreads();

    const int g = tid >> 3;  // local row 0..31
    const int l = tid & 7;   // lane-in-row
    const int row = row0 + g;
    float acc[5] = {0.f, 0.f, 0.f, 0.f, 0.f};
    for (int k = 0; k < 128; ++k) {
        float xv = sX[g][k];
        const float* w = &sW[k * 40 + l * 5];
#pragma unroll
        for (int j = 0; j < 5; ++j) acc[j] = fmaf(xv, w[j], acc[j]);
    }
#pragma unroll
    for (int j = 0; j < 5; ++j) acc[j] += sB[l * 5 + j];

    float m = acc[0];
#pragma unroll
    for (int j = 1; j < 5; ++j) m = fmaxf(m, acc[j]);
#pragma unroll
    for (int off = 1; off < 8; off <<= 1) m = fmaxf(m, __shfl_xor(m, off));
    float s = 0.f;
#pragma unroll
    for (int j = 0; j < 5; ++j) s += expf(acc[j] - m);
#pragma unroll
    for (int off = 1; off < 8; off <<= 1) s += __shfl_xor(s, off);
    float lse = m + logf(s);
    if (row < M) {
#pragma unroll
        for (int j = 0; j < 5; ++j) out[(size_t)row * 40 + l * 5 + j] = acc[j] - lse;
    }
}

// ---------------------------------------------------------------------------
// launch
// ---------------------------------------------------------------------------
extern "C" void kernel_launch(void* const* d_in, const int* in_sizes, int n_in,
                              void* d_out, int out_size, void* d_ws, size_t ws_size,
                              hipStream_t stream) {
    const float* x  = (const float*)d_in[0];
    const int*   ei = (const int*)d_in[1];
    const float* W1 = (const float*)d_in[2];
    const float* b1 = (const float*)d_in[3];
    const float* W2 = (const float*)d_in[4];
    const float* b2 = (const float*)d_in[5];
    const float* Wl = (const float*)d_in[6];
    const float* bl = (const float*)d_in[7];

    const int N = in_sizes[0] / FDIM;   // 50000
    const int E = in_sizes[1] / 2;      // 600000
    const int* src = ei;
    const int* dst = ei + E;

    float* out_lsm = (float*)d_out;                    // [N,40]
    float* x_emb   = (float*)d_out + (size_t)N * ODIM; // [N,128]

    // ---- workspace bump allocator (256 B aligned slots) ----
    char* w = (char*)d_ws;
    size_t off = 0;
    auto alloc = [&](size_t bytes) {
        void* p = w + off;
        off = (off + bytes + 255) & ~(size_t)255;
        return p;
    };
    int* count = (int*)alloc((size_t)N * 4);
    unsigned long long* states = (unsigned long long*)alloc(64 * 8);  // contiguous after count
    int* rowptr = (int*)alloc((size_t)(N + 1) * 4);
    int* cursor = (int*)alloc((size_t)N * 4);
    int* csr    = (int*)alloc((size_t)E * 4);
    float* dinv = (float*)alloc((size_t)N * 4);
    unsigned short* Wt1 = (unsigned short*)alloc(128 * 128 * 2);
    unsigned short* Wt2 = (unsigned short*)alloc(128 * 128 * 2);
    unsigned* bufA = (unsigned*)alloc((size_t)N * 64 * 4);
    unsigned* bufB = (unsigned*)alloc((size_t)N * 64 * 4);

    // zero count + states in ONE memset (they are adjacent slots)
    size_t zlen = ((char*)states - (char*)count) + 64 * 8;
    hipMemsetAsync(count, 0, zlen, stream);

    const int nsc = (N + 1023) / 1024;            // 49 scan blocks (<=64 states)
    count_conv_k<<<(E + 255) / 256, 256, 0, stream>>>(dst, count, E, W1, W2, Wt1, Wt2);
    scan_lookback_k<<<nsc, 256, 0, stream>>>(count, states, rowptr, cursor, dinv, N, nsc);
    fill_csr_k<<<(E + 255) / 256, 256, 0, stream>>>(src, dst, cursor, csr, E);

    const int gblocks = (N + 63) / 64;
    const int npb = (N + 3) / 4;                  // blocks per channel-pass
    // layer 1
    mfma_gemm_k<float><<<gblocks, 256, 0, stream>>>(x, Wt1, dinv, (unsigned short*)bufA, N);
    agg_pass_k<true, true><<<npb * 4, 256, 0, stream>>>(
        bufA, dinv, rowptr, csr, b1, bufB, N, npb);
    // layer 2
    mfma_gemm_k<unsigned short><<<gblocks, 256, 0, stream>>>(
        (const unsigned short*)bufB, Wt2, dinv, (unsigned short*)bufA, N);
    agg_pass_k<false, false><<<npb * 4, 256, 0, stream>>>(
        bufA, dinv, rowptr, csr, b2, x_emb, N, npb);
    // head
    logits_lsm_k<<<(N + 31) / 32, 256, 0, stream>>>(x_emb, Wl, bl, out_lsm, N);
}

// Round 10
// 283.937 us; speedup vs baseline: 1.3188x; 1.3188x over previous
//
#include <hip/hip_runtime.h>
#include <hip/hip_bf16.h>
#include <math.h>
#include <type_traits>

#define FDIM 128     // in/hid feature dim
#define ODIM 40      // output classes

typedef __attribute__((ext_vector_type(8))) short bf16x8;
typedef __attribute__((ext_vector_type(4))) float f32x4;

// ---- bf16 pack/unpack helpers (manual, RNE) --------------------------------
__device__ __forceinline__ float bf_lo(unsigned v) { return __uint_as_float(v << 16); }
__device__ __forceinline__ float bf_hi(unsigned v) { return __uint_as_float(v & 0xFFFF0000u); }
__device__ __forceinline__ unsigned f2bf(float f) {   // round-to-nearest-even
    unsigned u = __float_as_uint(f);
    return (u + 0x7FFFu + ((u >> 16) & 1u)) >> 16;
}

// ---------------------------------------------------------------------------
// 1) count in-degrees (dst atomics) + convert W1/W2 -> Wt bf16 (fused)
// ---------------------------------------------------------------------------
__global__ void count_conv_k(const int* __restrict__ dst, int* __restrict__ count, int E,
                             const float* __restrict__ W1, const float* __restrict__ W2,
                             unsigned short* __restrict__ Wt1, unsigned short* __restrict__ Wt2) {
    int e = blockIdx.x * 256 + threadIdx.x;
    if (e < E) atomicAdd(&count[dst[e]], 1);
    if (e < 2 * 16384) {                       // first 128 blocks also transpose weights
        const float* W = (e < 16384) ? W1 : W2;
        unsigned short* Wt = (e < 16384) ? Wt1 : Wt2;
        int j = e & 16383;
        int k = j >> 7, n = j & 127;
        Wt[n * 128 + k] = (unsigned short)f2bf(W[k * 128 + n]);
    }
}

// ---------------------------------------------------------------------------
// 2) single-pass decoupled-lookback exclusive scan over count[N] (1024/block)
// ---------------------------------------------------------------------------
#define FLG_AGG (1ull << 62)
#define FLG_INC (2ull << 62)
__global__ __launch_bounds__(256) void scan_lookback_k(
        const int* __restrict__ count, unsigned long long* __restrict__ states,
        int* __restrict__ rowptr, int* __restrict__ cursor,
        float* __restrict__ dinv, int n, int nblocks) {
    __shared__ int ts[256];
    __shared__ int s_prefix;
    const int b = blockIdx.x, tid = threadIdx.x;
    const int base = b * 1024 + tid * 4;
    int c[4];
    int s = 0;
#pragma unroll
    for (int j = 0; j < 4; ++j) {
        int i = base + j;
        c[j] = (i < n) ? count[i] : 0;
        s += c[j];
    }
    ts[tid] = s;
    __syncthreads();
    for (int off = 1; off < 256; off <<= 1) {   // Hillis-Steele inclusive
        int v = (tid >= off) ? ts[tid - off] : 0;
        __syncthreads();
        ts[tid] += v;
        __syncthreads();
    }
    const int total = ts[255];
    if (tid == 0) {
        if (b == 0) {
            __hip_atomic_store(&states[0], FLG_INC | (unsigned long long)total,
                               __ATOMIC_RELAXED, __HIP_MEMORY_SCOPE_AGENT);
            s_prefix = 0;
        } else {
            __hip_atomic_store(&states[b], FLG_AGG | (unsigned long long)total,
                               __ATOMIC_RELAXED, __HIP_MEMORY_SCOPE_AGENT);
            int prefix = 0;
            int j = b - 1;
            while (true) {
                unsigned long long v = __hip_atomic_load(&states[j], __ATOMIC_RELAXED,
                                                         __HIP_MEMORY_SCOPE_AGENT);
                unsigned long long f = v >> 62;
                if (f == 2ull) { prefix += (int)(v & 0xFFFFFFFFull); break; }
                if (f == 1ull) { prefix += (int)(v & 0xFFFFFFFFull); --j; }
                else __builtin_amdgcn_s_sleep(1);
            }
            __hip_atomic_store(&states[b], FLG_INC | (unsigned long long)(prefix + total),
                               __ATOMIC_RELAXED, __HIP_MEMORY_SCOPE_AGENT);
            s_prefix = prefix;
        }
    }
    __syncthreads();
    int excl = s_prefix + ts[tid] - s;
#pragma unroll
    for (int j = 0; j < 4; ++j) {
        int i = base + j;
        if (i < n) {
            rowptr[i] = excl;
            cursor[i] = excl;
            dinv[i] = rsqrtf((float)(c[j] + 1));
        }
        excl += c[j];
    }
    if (b == nblocks - 1 && tid == 255) rowptr[n] = s_prefix + total;
}

// ---------------------------------------------------------------------------
// 3) fill CSR: src ids grouped by dst
// ---------------------------------------------------------------------------
__global__ void fill_csr_k(const int* __restrict__ src, const int* __restrict__ dst,
                           int* __restrict__ cursor, int* __restrict__ csr_src, int E) {
    int e = blockIdx.x * blockDim.x + threadIdx.x;
    if (e < E) {
        int d = dst[e];
        int p = atomicAdd(&cursor[d], 1);
        csr_src[p] = src[e];
    }
}

// ---------------------------------------------------------------------------
// 4) MFMA GEMM: Cb[M,128](bf16) = (A[M,128] @ W) * dinv[row]
// ---------------------------------------------------------------------------
template <typename AT>
__global__ __launch_bounds__(256) void mfma_gemm_k(const AT* __restrict__ A,
                                                   const unsigned short* __restrict__ Wt,
                                                   const float* __restrict__ dinv,
                                                   unsigned short* __restrict__ Cb, int M) {
    __shared__ unsigned short As[64][136];   // row stride 272 B = 4 banks mod 32
    __shared__ unsigned short Bs[128][136];

    const int tid = threadIdx.x;
    const int row0 = blockIdx.x * 64;

    // ---- stage A (64 x 128) ----
    if constexpr (std::is_same_v<AT, float>) {
#pragma unroll
        for (int i = 0; i < 8; ++i) {        // 64 rows * 32 float4 = 2048
            int fidx = i * 256 + tid;
            int r = fidx >> 5, kq = fidx & 31;
            float4 v = make_float4(0.f, 0.f, 0.f, 0.f);
            int grow = row0 + r;
            if (grow < M) v = *(const float4*)&A[(size_t)grow * 128 + kq * 4];
            unsigned lo = f2bf(v.x) | (f2bf(v.y) << 16);
            unsigned hi = f2bf(v.z) | (f2bf(v.w) << 16);
            *(uint2*)&As[r][kq * 4] = make_uint2(lo, hi);
        }
    } else {
#pragma unroll
        for (int i = 0; i < 4; ++i) {        // 64 rows * 16 uint4 = 1024
            int fidx = i * 256 + tid;
            int r = fidx >> 4, kq = fidx & 15;
            uint4 v = make_uint4(0, 0, 0, 0);
            int grow = row0 + r;
            if (grow < M) v = *(const uint4*)&A[(size_t)grow * 128 + kq * 8];
            *(uint4*)&As[r][kq * 8] = v;
        }
    }
    // ---- stage B (128 x 128) ----
#pragma unroll
    for (int i = 0; i < 8; ++i) {            // 128 rows * 16 uint4 = 2048
        int fidx = i * 256 + tid;
        int r = fidx >> 4, kq = fidx & 15;
        *(uint4*)&Bs[r][kq * 8] = *(const uint4*)&Wt[(size_t)r * 128 + kq * 8];
    }
    __syncthreads();

    // ---- compute ----
    const int lane = tid & 63;
    const int wv = tid >> 6;       // wave 0..3 -> cols wv*32 .. +31
    const int n0 = wv * 32;
    const int mrow = lane & 15;
    const int quad = lane >> 4;

    f32x4 acc[4][2];
#pragma unroll
    for (int mt = 0; mt < 4; ++mt)
#pragma unroll
        for (int nt = 0; nt < 2; ++nt) acc[mt][nt] = (f32x4){0.f, 0.f, 0.f, 0.f};

#pragma unroll
    for (int kk = 0; kk < 128; kk += 32) {
        int ko = kk + quad * 8;
        bf16x8 af[4], bfr[2];
#pragma unroll
        for (int mt = 0; mt < 4; ++mt) af[mt] = *(const bf16x8*)&As[mt * 16 + mrow][ko];
#pragma unroll
        for (int nt = 0; nt < 2; ++nt) bfr[nt] = *(const bf16x8*)&Bs[n0 + nt * 16 + mrow][ko];
#pragma unroll
        for (int mt = 0; mt < 4; ++mt)
#pragma unroll
            for (int nt = 0; nt < 2; ++nt)
                acc[mt][nt] = __builtin_amdgcn_mfma_f32_16x16x32_bf16(af[mt], bfr[nt], acc[mt][nt], 0, 0, 0);
    }

    // ---- epilogue: C layout col=lane&15, row=quad*4+reg ----
#pragma unroll
    for (int mt = 0; mt < 4; ++mt) {
#pragma unroll
        for (int reg = 0; reg < 4; ++reg) {
            int grow = row0 + mt * 16 + quad * 4 + reg;
            if (grow < M) {
                float sc = dinv[grow];
#pragma unroll
                for (int nt = 0; nt < 2; ++nt) {
                    int col = n0 + nt * 16 + mrow;
                    Cb[(size_t)grow * 128 + col] = (unsigned short)f2bf(acc[mt][nt][reg] * sc);
                }
            }
        }
    }
}

// ---------------------------------------------------------------------------
// 5) aggregate: out[d,:] = act( dinv[d]*(g[d,:] + sum_{s in N(d)} g[s,:]) + b )
//    256-thread blocks = 4 waves, ONE dst node per wave, lane = 2 channels.
//    (R8 used 64-thr blocks: HW caps ~16 WGs/CU -> only 16 waves/CU. 256-thr
//    blocks give 8 WGs x 4 waves = 32 waves/CU = full occupancy for the
//    latency-bound gather.) Full-row 256 B wave-loads, unroll 8.
// ---------------------------------------------------------------------------
template <bool RELU, bool OUT_BF16>
__global__ __launch_bounds__(256) void aggregate_k(const unsigned* __restrict__ g,
                                                   const float* __restrict__ dinv,
                                                   const int* __restrict__ rowptr,
                                                   const int* __restrict__ csr_src,
                                                   const float* __restrict__ bias,
                                                   void* __restrict__ outv, int n) {
    const int d = blockIdx.x * 4 + (threadIdx.x >> 6);
    if (d >= n) return;
    const int c = threadIdx.x & 63;       // lane: channels 2c, 2c+1
    unsigned self = g[(size_t)d * 64 + c];
    float ax = bf_lo(self), ay = bf_hi(self);
    int e = rowptr[d], end = rowptr[d + 1];
    for (; e + 7 < end; e += 8) {
        int s0 = csr_src[e],     s1 = csr_src[e + 1], s2 = csr_src[e + 2], s3 = csr_src[e + 3];
        int s4 = csr_src[e + 4], s5 = csr_src[e + 5], s6 = csr_src[e + 6], s7 = csr_src[e + 7];
        unsigned v0 = g[(size_t)s0 * 64 + c], v1 = g[(size_t)s1 * 64 + c];
        unsigned v2 = g[(size_t)s2 * 64 + c], v3 = g[(size_t)s3 * 64 + c];
        unsigned v4 = g[(size_t)s4 * 64 + c], v5 = g[(size_t)s5 * 64 + c];
        unsigned v6 = g[(size_t)s6 * 64 + c], v7 = g[(size_t)s7 * 64 + c];
        ax += (bf_lo(v0) + bf_lo(v1)) + (bf_lo(v2) + bf_lo(v3))
            + (bf_lo(v4) + bf_lo(v5)) + (bf_lo(v6) + bf_lo(v7));
        ay += (bf_hi(v0) + bf_hi(v1)) + (bf_hi(v2) + bf_hi(v3))
            + (bf_hi(v4) + bf_hi(v5)) + (bf_hi(v6) + bf_hi(v7));
    }
    for (; e < end; ++e) {
        unsigned v = g[(size_t)csr_src[e] * 64 + c];
        ax += bf_lo(v);
        ay += bf_hi(v);
    }
    float sc = dinv[d];
    float ox = fmaf(sc, ax, bias[2 * c]);
    float oy = fmaf(sc, ay, bias[2 * c + 1]);
    if (RELU) { ox = fmaxf(ox, 0.f); oy = fmaxf(oy, 0.f); }
    if constexpr (OUT_BF16) {
        ((unsigned*)outv)[(size_t)d * 64 + c] = f2bf(ox) | (f2bf(oy) << 16);
    } else {
        ((float2*)outv)[(size_t)d * 64 + c] = make_float2(ox, oy);
    }
}

// ---------------------------------------------------------------------------
// 6) logits = x_emb @ Wl + bl; log_softmax over 40 cols.
// ---------------------------------------------------------------------------
__global__ __launch_bounds__(256) void logits_lsm_k(const float* __restrict__ xe,
                                                    const float* __restrict__ Wl,
                                                    const float* __restrict__ bl,
                                                    float* __restrict__ out, int M) {
    __shared__ float sW[128 * 40];
    __shared__ float sX[32][132];
    __shared__ float sB[40];
    const int tid = threadIdx.x;
    const int row0 = blockIdx.x * 32;

    for (int i = tid; i < (128 * 40) / 4; i += 256)
        ((float4*)sW)[i] = ((const float4*)Wl)[i];
    if (tid < 40) sB[tid] = bl[tid];
    for (int i = tid; i < 32 * 32; i += 256) {
        int r = i >> 5, cq = i & 31;
        float4 v = make_float4(0.f, 0.f, 0.f, 0.f);
        if (row0 + r < M) v = *(const float4*)&xe[(size_t)(row0 + r) * 128 + cq * 4];
        *(float4*)&sX[r][cq * 4] = v;
    }
    __syncthreads();

    const int g = tid >> 3;  // local row 0..31
    const int l = tid & 7;   // lane-in-row
    const int row = row0 + g;
    float acc[5] = {0.f, 0.f, 0.f, 0.f, 0.f};
    for (int k = 0; k < 128; ++k) {
        float xv = sX[g][k];
        const float* w = &sW[k * 40 + l * 5];
#pragma unroll
        for (int j = 0; j < 5; ++j) acc[j] = fmaf(xv, w[j], acc[j]);
    }
#pragma unroll
    for (int j = 0; j < 5; ++j) acc[j] += sB[l * 5 + j];

    float m = acc[0];
#pragma unroll
    for (int j = 1; j < 5; ++j) m = fmaxf(m, acc[j]);
#pragma unroll
    for (int off = 1; off < 8; off <<= 1) m = fmaxf(m, __shfl_xor(m, off));
    float s = 0.f;
#pragma unroll
    for (int j = 0; j < 5; ++j) s += expf(acc[j] - m);
#pragma unroll
    for (int off = 1; off < 8; off <<= 1) s += __shfl_xor(s, off);
    float lse = m + logf(s);
    if (row < M) {
#pragma unroll
        for (int j = 0; j < 5; ++j) out[(size_t)row * 40 + l * 5 + j] = acc[j] - lse;
    }
}

// ---------------------------------------------------------------------------
// launch
// ---------------------------------------------------------------------------
extern "C" void kernel_launch(void* const* d_in, const int* in_sizes, int n_in,
                              void* d_out, int out_size, void* d_ws, size_t ws_size,
                              hipStream_t stream) {
    const float* x  = (const float*)d_in[0];
    const int*   ei = (const int*)d_in[1];
    const float* W1 = (const float*)d_in[2];
    const float* b1 = (const float*)d_in[3];
    const float* W2 = (const float*)d_in[4];
    const float* b2 = (const float*)d_in[5];
    const float* Wl = (const float*)d_in[6];
    const float* bl = (const float*)d_in[7];

    const int N = in_sizes[0] / FDIM;   // 50000
    const int E = in_sizes[1] / 2;      // 600000
    const int* src = ei;
    const int* dst = ei + E;

    float* out_lsm = (float*)d_out;                    // [N,40]
    float* x_emb   = (float*)d_out + (size_t)N * ODIM; // [N,128]

    // ---- workspace bump allocator (256 B aligned slots) ----
    char* w = (char*)d_ws;
    size_t off = 0;
    auto alloc = [&](size_t bytes) {
        void* p = w + off;
        off = (off + bytes + 255) & ~(size_t)255;
        return p;
    };
    int* count = (int*)alloc((size_t)N * 4);
    unsigned long long* states = (unsigned long long*)alloc(64 * 8);  // contiguous after count
    int* rowptr = (int*)alloc((size_t)(N + 1) * 4);
    int* cursor = (int*)alloc((size_t)N * 4);
    int* csr    = (int*)alloc((size_t)E * 4);
    float* dinv = (float*)alloc((size_t)N * 4);
    unsigned short* Wt1 = (unsigned short*)alloc(128 * 128 * 2);
    unsigned short* Wt2 = (unsigned short*)alloc(128 * 128 * 2);
    unsigned* bufA = (unsigned*)alloc((size_t)N * 64 * 4);
    unsigned* bufB = (unsigned*)alloc((size_t)N * 64 * 4);

    // zero count + states in ONE memset (they are adjacent slots)
    size_t zlen = ((char*)states - (char*)count) + 64 * 8;
    hipMemsetAsync(count, 0, zlen, stream);

    const int nsc = (N + 1023) / 1024;            // 49 scan blocks (<=64 states)
    count_conv_k<<<(E + 255) / 256, 256, 0, stream>>>(dst, count, E, W1, W2, Wt1, Wt2);
    scan_lookback_k<<<nsc, 256, 0, stream>>>(count, states, rowptr, cursor, dinv, N, nsc);
    fill_csr_k<<<(E + 255) / 256, 256, 0, stream>>>(src, dst, cursor, csr, E);

    const int gblocks = (N + 63) / 64;
    const int ablocks = (N + 3) / 4;
    // layer 1
    mfma_gemm_k<float><<<gblocks, 256, 0, stream>>>(x, Wt1, dinv, (unsigned short*)bufA, N);
    aggregate_k<true, true><<<ablocks, 256, 0, stream>>>(bufA, dinv, rowptr, csr, b1, bufB, N);
    // layer 2
    mfma_gemm_k<unsigned short><<<gblocks, 256, 0, stream>>>(
        (const unsigned short*)bufB, Wt2, dinv, (unsigned short*)bufA, N);
    aggregate_k<false, false><<<ablocks, 256, 0, stream>>>(bufA, dinv, rowptr, csr, b2, x_emb, N);
    // head
    logits_lsm_k<<<(N + 31) / 32, 256, 0, stream>>>(x_emb, Wl, bl, out_lsm, N);
}

// Round 11
// 273.175 us; speedup vs baseline: 1.3707x; 1.0394x over previous
//
#include <hip/hip_runtime.h>
#include <hip/hip_bf16.h>
#include <math.h>
#include <type_traits>

#define FDIM 128     // in/hid feature dim
#define ODIM 40      // output classes

typedef __attribute__((ext_vector_type(8))) short bf16x8;
typedef __attribute__((ext_vector_type(4))) float f32x4;

// ---- bf16 pack/unpack helpers (manual, RNE) --------------------------------
__device__ __forceinline__ float bf_lo(unsigned v) { return __uint_as_float(v << 16); }
__device__ __forceinline__ float bf_hi(unsigned v) { return __uint_as_float(v & 0xFFFF0000u); }
__device__ __forceinline__ unsigned f2bf(float f) {   // round-to-nearest-even
    unsigned u = __float_as_uint(f);
    return (u + 0x7FFFu + ((u >> 16) & 1u)) >> 16;
}

// ---------------------------------------------------------------------------
// 1) count in-degrees (dst atomics) + convert W1/W2 -> Wt bf16 (fused)
// ---------------------------------------------------------------------------
__global__ void count_conv_k(const int* __restrict__ dst, int* __restrict__ count, int E,
                             const float* __restrict__ W1, const float* __restrict__ W2,
                             unsigned short* __restrict__ Wt1, unsigned short* __restrict__ Wt2) {
    int e = blockIdx.x * 256 + threadIdx.x;
    if (e < E) atomicAdd(&count[dst[e]], 1);
    if (e < 2 * 16384) {                       // first 128 blocks also transpose weights
        const float* W = (e < 16384) ? W1 : W2;
        unsigned short* Wt = (e < 16384) ? Wt1 : Wt2;
        int j = e & 16383;
        int k = j >> 7, n = j & 127;
        Wt[n * 128 + k] = (unsigned short)f2bf(W[k * 128 + n]);
    }
}

// ---------------------------------------------------------------------------
// 2) single-pass decoupled-lookback exclusive scan over count[N] (1024/block)
// ---------------------------------------------------------------------------
#define FLG_AGG (1ull << 62)
#define FLG_INC (2ull << 62)
__global__ __launch_bounds__(256) void scan_lookback_k(
        const int* __restrict__ count, unsigned long long* __restrict__ states,
        int* __restrict__ rowptr, int* __restrict__ cursor,
        float* __restrict__ dinv, int n, int nblocks) {
    __shared__ int ts[256];
    __shared__ int s_prefix;
    const int b = blockIdx.x, tid = threadIdx.x;
    const int base = b * 1024 + tid * 4;
    int c[4];
    int s = 0;
#pragma unroll
    for (int j = 0; j < 4; ++j) {
        int i = base + j;
        c[j] = (i < n) ? count[i] : 0;
        s += c[j];
    }
    ts[tid] = s;
    __syncthreads();
    for (int off = 1; off < 256; off <<= 1) {   // Hillis-Steele inclusive
        int v = (tid >= off) ? ts[tid - off] : 0;
        __syncthreads();
        ts[tid] += v;
        __syncthreads();
    }
    const int total = ts[255];
    if (tid == 0) {
        if (b == 0) {
            __hip_atomic_store(&states[0], FLG_INC | (unsigned long long)total,
                               __ATOMIC_RELAXED, __HIP_MEMORY_SCOPE_AGENT);
            s_prefix = 0;
        } else {
            __hip_atomic_store(&states[b], FLG_AGG | (unsigned long long)total,
                               __ATOMIC_RELAXED, __HIP_MEMORY_SCOPE_AGENT);
            int prefix = 0;
            int j = b - 1;
            while (true) {
                unsigned long long v = __hip_atomic_load(&states[j], __ATOMIC_RELAXED,
                                                         __HIP_MEMORY_SCOPE_AGENT);
                unsigned long long f = v >> 62;
                if (f == 2ull) { prefix += (int)(v & 0xFFFFFFFFull); break; }
                if (f == 1ull) { prefix += (int)(v & 0xFFFFFFFFull); --j; }
                else __builtin_amdgcn_s_sleep(1);
            }
            __hip_atomic_store(&states[b], FLG_INC | (unsigned long long)(prefix + total),
                               __ATOMIC_RELAXED, __HIP_MEMORY_SCOPE_AGENT);
            s_prefix = prefix;
        }
    }
    __syncthreads();
    int excl = s_prefix + ts[tid] - s;
#pragma unroll
    for (int j = 0; j < 4; ++j) {
        int i = base + j;
        if (i < n) {
            rowptr[i] = excl;
            cursor[i] = excl;
            dinv[i] = rsqrtf((float)(c[j] + 1));
        }
        excl += c[j];
    }
    if (b == nblocks - 1 && tid == 255) rowptr[n] = s_prefix + total;
}

// ---------------------------------------------------------------------------
// shared MFMA GEMM body: Cb[M,128](bf16) = A[M,128] @ W  (NO dinv scale here —
// deferred to the aggregate so gemm1 is independent of the scan/CSR chain).
// ---------------------------------------------------------------------------
template <typename AT>
__device__ __forceinline__ void gemm_body(unsigned short (*As)[136], unsigned short (*Bs)[136],
                                          const AT* __restrict__ A,
                                          const unsigned short* __restrict__ Wt,
                                          unsigned short* __restrict__ Cb, int M, int row0) {
    const int tid = threadIdx.x;

    // ---- stage A (64 x 128) ----
    if constexpr (std::is_same_v<AT, float>) {
#pragma unroll
        for (int i = 0; i < 8; ++i) {        // 64 rows * 32 float4 = 2048
            int fidx = i * 256 + tid;
            int r = fidx >> 5, kq = fidx & 31;
            float4 v = make_float4(0.f, 0.f, 0.f, 0.f);
            int grow = row0 + r;
            if (grow < M) v = *(const float4*)&A[(size_t)grow * 128 + kq * 4];
            unsigned lo = f2bf(v.x) | (f2bf(v.y) << 16);
            unsigned hi = f2bf(v.z) | (f2bf(v.w) << 16);
            *(uint2*)&As[r][kq * 4] = make_uint2(lo, hi);
        }
    } else {
#pragma unroll
        for (int i = 0; i < 4; ++i) {        // 64 rows * 16 uint4 = 1024
            int fidx = i * 256 + tid;
            int r = fidx >> 4, kq = fidx & 15;
            uint4 v = make_uint4(0, 0, 0, 0);
            int grow = row0 + r;
            if (grow < M) v = *(const uint4*)&A[(size_t)grow * 128 + kq * 8];
            *(uint4*)&As[r][kq * 8] = v;
        }
    }
    // ---- stage B (128 x 128) ----
#pragma unroll
    for (int i = 0; i < 8; ++i) {            // 128 rows * 16 uint4 = 2048
        int fidx = i * 256 + tid;
        int r = fidx >> 4, kq = fidx & 15;
        *(uint4*)&Bs[r][kq * 8] = *(const uint4*)&Wt[(size_t)r * 128 + kq * 8];
    }
    __syncthreads();

    // ---- compute ----
    const int lane = tid & 63;
    const int wv = tid >> 6;       // wave 0..3 -> cols wv*32 .. +31
    const int n0 = wv * 32;
    const int mrow = lane & 15;
    const int quad = lane >> 4;

    f32x4 acc[4][2];
#pragma unroll
    for (int mt = 0; mt < 4; ++mt)
#pragma unroll
        for (int nt = 0; nt < 2; ++nt) acc[mt][nt] = (f32x4){0.f, 0.f, 0.f, 0.f};

#pragma unroll
    for (int kk = 0; kk < 128; kk += 32) {
        int ko = kk + quad * 8;
        bf16x8 af[4], bfr[2];
#pragma unroll
        for (int mt = 0; mt < 4; ++mt) af[mt] = *(const bf16x8*)&As[mt * 16 + mrow][ko];
#pragma unroll
        for (int nt = 0; nt < 2; ++nt) bfr[nt] = *(const bf16x8*)&Bs[n0 + nt * 16 + mrow][ko];
#pragma unroll
        for (int mt = 0; mt < 4; ++mt)
#pragma unroll
            for (int nt = 0; nt < 2; ++nt)
                acc[mt][nt] = __builtin_amdgcn_mfma_f32_16x16x32_bf16(af[mt], bfr[nt], acc[mt][nt], 0, 0, 0);
    }

    // ---- epilogue: C layout col=lane&15, row=quad*4+reg ----
#pragma unroll
    for (int mt = 0; mt < 4; ++mt) {
#pragma unroll
        for (int reg = 0; reg < 4; ++reg) {
            int grow = row0 + mt * 16 + quad * 4 + reg;
            if (grow < M) {
#pragma unroll
                for (int nt = 0; nt < 2; ++nt) {
                    int col = n0 + nt * 16 + mrow;
                    Cb[(size_t)grow * 128 + col] = (unsigned short)f2bf(acc[mt][nt][reg]);
                }
            }
        }
    }
}

// ---------------------------------------------------------------------------
// 3+4a) FUSED: fill CSR (scatter) overlapped with layer-1 GEMM.
//    Blocks [0,gblocks): MFMA GEMM h1 = x @ W1 (needs only x, Wt1).
//    Blocks [gblocks,...): fill_csr (needs cursor from scan).
//    Complementary pipes (MFMA/LDS vs atomics/VMEM) co-schedule on CUs.
// ---------------------------------------------------------------------------
__global__ __launch_bounds__(256) void fill_gemm1_k(
        const int* __restrict__ src, const int* __restrict__ dst,
        int* __restrict__ cursor, int* __restrict__ csr, int E,
        const float* __restrict__ x, const unsigned short* __restrict__ Wt1,
        unsigned short* __restrict__ h1, int M, int gblocks) {
    __shared__ unsigned short As[64][136];   // row stride 272 B = 4 banks mod 32
    __shared__ unsigned short Bs[128][136];
    if ((int)blockIdx.x < gblocks) {
        gemm_body<float>(As, Bs, x, Wt1, h1, M, blockIdx.x * 64);
    } else {
        int e = ((int)blockIdx.x - gblocks) * 256 + threadIdx.x;
        if (e < E) {
            int d = dst[e];
            int p = atomicAdd(&cursor[d], 1);
            csr[p] = src[e];
        }
    }
}

// ---------------------------------------------------------------------------
// 4b) layer-2 GEMM (standalone): h2 = h2in @ W2 (bf16 A path, no scale)
// ---------------------------------------------------------------------------
__global__ __launch_bounds__(256) void mfma_gemm2_k(const unsigned short* __restrict__ A,
                                                    const unsigned short* __restrict__ Wt,
                                                    unsigned short* __restrict__ Cb, int M) {
    __shared__ unsigned short As[64][136];
    __shared__ unsigned short Bs[128][136];
    gemm_body<unsigned short>(As, Bs, A, Wt, Cb, M, blockIdx.x * 64);
}

// ---------------------------------------------------------------------------
// 5) aggregate with DEFERRED norm: out[d,:] = act( dinv[d]*( dinv[d]*h[d,:]
//      + sum_s dinv[s]*h[s,:] ) + b ).  h is UNSCALED bf16 from the GEMM.
//    One 64-lane wave per dst node (R8 form — best measured: independent wave
//    retirement load-balances the degree skew). dinv is 200 KB, L2-hot;
//    per-edge dinv[s] is a wave-uniform broadcast load. Unroll 8.
// ---------------------------------------------------------------------------
template <bool RELU, bool OUT_BF16>
__global__ __launch_bounds__(64) void aggregate_k(const unsigned* __restrict__ g,
                                                  const float* __restrict__ dinv,
                                                  const int* __restrict__ rowptr,
                                                  const int* __restrict__ csr_src,
                                                  const float* __restrict__ bias,
                                                  void* __restrict__ outv, int n) {
    const int d = blockIdx.x;
    const int c = threadIdx.x;            // lane: channels 2c, 2c+1
    const float dd = dinv[d];
    unsigned self = g[(size_t)d * 64 + c];
    float ax = dd * bf_lo(self), ay = dd * bf_hi(self);   // self-loop: dinv[d]*h[d]
    int e = rowptr[d], end = rowptr[d + 1];
    for (; e + 7 < end; e += 8) {
        int s0 = csr_src[e],     s1 = csr_src[e + 1], s2 = csr_src[e + 2], s3 = csr_src[e + 3];
        int s4 = csr_src[e + 4], s5 = csr_src[e + 5], s6 = csr_src[e + 6], s7 = csr_src[e + 7];
        float w0 = dinv[s0], w1 = dinv[s1], w2 = dinv[s2], w3 = dinv[s3];
        float w4 = dinv[s4], w5 = dinv[s5], w6 = dinv[s6], w7 = dinv[s7];
        unsigned v0 = g[(size_t)s0 * 64 + c], v1 = g[(size_t)s1 * 64 + c];
        unsigned v2 = g[(size_t)s2 * 64 + c], v3 = g[(size_t)s3 * 64 + c];
        unsigned v4 = g[(size_t)s4 * 64 + c], v5 = g[(size_t)s5 * 64 + c];
        unsigned v6 = g[(size_t)s6 * 64 + c], v7 = g[(size_t)s7 * 64 + c];
        ax = fmaf(w0, bf_lo(v0), ax); ay = fmaf(w0, bf_hi(v0), ay);
        ax = fmaf(w1, bf_lo(v1), ax); ay = fmaf(w1, bf_hi(v1), ay);
        ax = fmaf(w2, bf_lo(v2), ax); ay = fmaf(w2, bf_hi(v2), ay);
        ax = fmaf(w3, bf_lo(v3), ax); ay = fmaf(w3, bf_hi(v3), ay);
        ax = fmaf(w4, bf_lo(v4), ax); ay = fmaf(w4, bf_hi(v4), ay);
        ax = fmaf(w5, bf_lo(v5), ax); ay = fmaf(w5, bf_hi(v5), ay);
        ax = fmaf(w6, bf_lo(v6), ax); ay = fmaf(w6, bf_hi(v6), ay);
        ax = fmaf(w7, bf_lo(v7), ax); ay = fmaf(w7, bf_hi(v7), ay);
    }
    for (; e < end; ++e) {
        int s = csr_src[e];
        float w = dinv[s];
        unsigned v = g[(size_t)s * 64 + c];
        ax = fmaf(w, bf_lo(v), ax);
        ay = fmaf(w, bf_hi(v), ay);
    }
    float ox = fmaf(dd, ax, bias[2 * c]);
    float oy = fmaf(dd, ay, bias[2 * c + 1]);
    if (RELU) { ox = fmaxf(ox, 0.f); oy = fmaxf(oy, 0.f); }
    if constexpr (OUT_BF16) {
        ((unsigned*)outv)[(size_t)d * 64 + c] = f2bf(ox) | (f2bf(oy) << 16);
    } else {
        ((float2*)outv)[(size_t)d * 64 + c] = make_float2(ox, oy);
    }
}

// ---------------------------------------------------------------------------
// 6) logits = x_emb @ Wl + bl; log_softmax over 40 cols.
// ---------------------------------------------------------------------------
__global__ __launch_bounds__(256) void logits_lsm_k(const float* __restrict__ xe,
                                                    const float* __restrict__ Wl,
                                                    const float* __restrict__ bl,
                                                    float* __restrict__ out, int M) {
    __shared__ float sW[128 * 40];
    __shared__ float sX[32][132];
    __shared__ float sB[40];
    const int tid = threadIdx.x;
    const int row0 = blockIdx.x * 32;

    for (int i = tid; i < (128 * 40) / 4; i += 256)
        ((float4*)sW)[i] = ((const float4*)Wl)[i];
    if (tid < 40) sB[tid] = bl[tid];
    for (int i = tid; i < 32 * 32; i += 256) {
        int r = i >> 5, cq = i & 31;
        float4 v = make_float4(0.f, 0.f, 0.f, 0.f);
        if (row0 + r < M) v = *(const float4*)&xe[(size_t)(row0 + r) * 128 + cq * 4];
        *(float4*)&sX[r][cq * 4] = v;
    }
    __syncthreads();

    const int g = tid >> 3;  // local row 0..31
    const int l = tid & 7;   // lane-in-row
    const int row = row0 + g;
    float acc[5] = {0.f, 0.f, 0.f, 0.f, 0.f};
    for (int k = 0; k < 128; ++k) {
        float xv = sX[g][k];
        const float* w = &sW[k * 40 + l * 5];
#pragma unroll
        for (int j = 0; j < 5; ++j) acc[j] = fmaf(xv, w[j], acc[j]);
    }
#pragma unroll
    for (int j = 0; j < 5; ++j) acc[j] += sB[l * 5 + j];

    float m = acc[0];
#pragma unroll
    for (int j = 1; j < 5; ++j) m = fmaxf(m, acc[j]);
#pragma unroll
    for (int off = 1; off < 8; off <<= 1) m = fmaxf(m, __shfl_xor(m, off));
    float s = 0.f;
#pragma unroll
    for (int j = 0; j < 5; ++j) s += expf(acc[j] - m);
#pragma unroll
    for (int off = 1; off < 8; off <<= 1) s += __shfl_xor(s, off);
    float lse = m + logf(s);
    if (row < M) {
#pragma unroll
        for (int j = 0; j < 5; ++j) out[(size_t)row * 40 + l * 5 + j] = acc[j] - lse;
    }
}

// ---------------------------------------------------------------------------
// launch
// ---------------------------------------------------------------------------
extern "C" void kernel_launch(void* const* d_in, const int* in_sizes, int n_in,
                              void* d_out, int out_size, void* d_ws, size_t ws_size,
                              hipStream_t stream) {
    const float* x  = (const float*)d_in[0];
    const int*   ei = (const int*)d_in[1];
    const float* W1 = (const float*)d_in[2];
    const float* b1 = (const float*)d_in[3];
    const float* W2 = (const float*)d_in[4];
    const float* b2 = (const float*)d_in[5];
    const float* Wl = (const float*)d_in[6];
    const float* bl = (const float*)d_in[7];

    const int N = in_sizes[0] / FDIM;   // 50000
    const int E = in_sizes[1] / 2;      // 600000
    const int* src = ei;
    const int* dst = ei + E;

    float* out_lsm = (float*)d_out;                    // [N,40]
    float* x_emb   = (float*)d_out + (size_t)N * ODIM; // [N,128]

    // ---- workspace bump allocator (256 B aligned slots) ----
    char* w = (char*)d_ws;
    size_t off = 0;
    auto alloc = [&](size_t bytes) {
        void* p = w + off;
        off = (off + bytes + 255) & ~(size_t)255;
        return p;
    };
    int* count = (int*)alloc((size_t)N * 4);
    unsigned long long* states = (unsigned long long*)alloc(64 * 8);  // contiguous after count
    int* rowptr = (int*)alloc((size_t)(N + 1) * 4);
    int* cursor = (int*)alloc((size_t)N * 4);
    int* csr    = (int*)alloc((size_t)E * 4);
    float* dinv = (float*)alloc((size_t)N * 4);
    unsigned short* Wt1 = (unsigned short*)alloc(128 * 128 * 2);
    unsigned short* Wt2 = (unsigned short*)alloc(128 * 128 * 2);
    unsigned* bufA = (unsigned*)alloc((size_t)N * 64 * 4);
    unsigned* bufB = (unsigned*)alloc((size_t)N * 64 * 4);

    // zero count + states in ONE memset (they are adjacent slots)
    size_t zlen = ((char*)states - (char*)count) + 64 * 8;
    hipMemsetAsync(count, 0, zlen, stream);

    const int nsc = (N + 1023) / 1024;            // 49 scan blocks (<=64 states)
    const int gblocks = (N + 63) / 64;            // 782 GEMM tiles
    const int fblocks = (E + 255) / 256;          // 2344 fill blocks

    count_conv_k<<<fblocks, 256, 0, stream>>>(dst, count, E, W1, W2, Wt1, Wt2);
    scan_lookback_k<<<nsc, 256, 0, stream>>>(count, states, rowptr, cursor, dinv, N, nsc);
    // fill CSR overlapped with layer-1 GEMM (independent work)
    fill_gemm1_k<<<gblocks + fblocks, 256, 0, stream>>>(
        src, dst, cursor, csr, E, x, Wt1, (unsigned short*)bufA, N, gblocks);
    // layer 1 aggregate (+bias,+relu) -> bufB bf16
    aggregate_k<true, true><<<N, 64, 0, stream>>>(bufA, dinv, rowptr, csr, b1, bufB, N);
    // layer 2
    mfma_gemm2_k<<<gblocks, 256, 0, stream>>>(
        (const unsigned short*)bufB, Wt2, (unsigned short*)bufA, N);
    aggregate_k<false, false><<<N, 64, 0, stream>>>(bufA, dinv, rowptr, csr, b2, x_emb, N);
    // head
    logits_lsm_k<<<(N + 31) / 32, 256, 0, stream>>>(x_emb, Wl, bl, out_lsm, N);
}